// Round 2
// baseline (348.007 us; speedup 1.0000x reference)
//
#include <hip/hip_runtime.h>
#include <math.h>

// B=16, H=W=28, C=1, KSIZE=5, KNUM=16, VALID stride-1 -> OH=OW=24, P=576.
#define BATCH 16
#define H     28
#define W     28
#define KS    5
#define KN    16
#define OHW   24
#define P     576           // = 9 * 64 exactly
#define NTHR  256           // 4 waves; one p-row per wave
#define MU_OUT_ELEMS (BATCH * P * KN)

typedef float vfloat4 __attribute__((ext_vector_type(4)));

__global__ __launch_bounds__(NTHR) void vdp_fused_kernel(
    const float* __restrict__ mu_in,    // [16,28,28,1]
    const float* __restrict__ w_mu,     // [5,5,1,16]
    const float* __restrict__ w_sigma,  // [16]
    float* __restrict__ out)
{
    __shared__ float mu_s[H * W];         // 3.1 KB
    __shared__ float wmu_s[KS * KS * KN]; // 1.6 KB
    __shared__ float sp_s[KN];

    const int tid  = threadIdx.x;
    const int wave = tid >> 6;
    const int lane = tid & 63;

    const int blocks_per_b = P / 4;     // 144 (4 p-rows per block, 1 per wave)
    const int b = blockIdx.x / blocks_per_b;
    const int p = (blockIdx.x % blocks_per_b) * 4 + wave;

    // Stage image, conv weights, softplus scales. ONE barrier total.
    const float* mu_b = mu_in + b * (H * W);
    for (int i = tid; i < H * W; i += NTHR) mu_s[i] = mu_b[i];
    for (int i = tid; i < KS * KS * KN; i += NTHR) wmu_s[i] = w_mu[i];
    if (tid < KN) sp_s[tid] = log1pf(expf(w_sigma[tid]));
    __syncthreads();

    const int ph = p / OHW;
    const int pw = p % OHW;

    // Patch p (wave-uniform LDS broadcast reads).
    float Xp[KS * KS];
    #pragma unroll
    for (int kh = 0; kh < KS; ++kh)
        #pragma unroll
        for (int kw = 0; kw < KS; ++kw)
            Xp[kh * KS + kw] = mu_s[(ph + kh) * W + (pw + kw)];

    // mu_out row: lanes 0..15, one output channel each.
    if (lane < KN) {
        float acc = 0.f;
        #pragma unroll
        for (int j = 0; j < KS * KS; ++j)
            acc += Xp[j] * wmu_s[j * KN + lane];
        out[(b * P + p) * KN + lane] = acc;
    }

    // This lane's 4 channels: c = lane&3 -> channels 4c..4c+3.
    const int c = lane & 3;
    const float sc0 = sp_s[4 * c + 0];
    const float sc1 = sp_s[4 * c + 1];
    const float sc2 = sp_s[4 * c + 2];
    const float sc3 = sp_s[4 * c + 3];

    vfloat4* rowp = (vfloat4*)(out + MU_OUT_ELEMS + (size_t)(b * P + p) * (P * KN));

    // Interleaved compute->store: for each r, compute Gram chunk
    // g = <Xp, X_{64r+lane}>, then immediately emit its 4 contiguous
    // 1 KB wave-stores (s = 4r+t). No barriers.
    // A/B vs previous round: PLAIN stores (no nontemporal flag) — testing
    // whether the nt path's L2-bypass was collapsing write-combining.
    #pragma unroll
    for (int r = 0; r < 9; ++r) {
        const int q  = r * 64 + lane;
        const int qh = q / OHW;
        const int qw = q % OHW;
        const float* mq = &mu_s[qh * W + qw];
        float g = 0.f;
        #pragma unroll
        for (int kh = 0; kh < KS; ++kh)
            #pragma unroll
            for (int kw = 0; kw < KS; ++kw)
                g += Xp[kh * KS + kw] * mq[kh * W + kw];

        // Store s = 4r+t, lane i -> float4 index f = 64s+i, row pos
        // q' = 16s+(i>>2), held by lane 16*t + (i>>2) of this chunk.
        #pragma unroll
        for (int t = 0; t < 4; ++t) {
            const int s = 4 * r + t;
            const float gq = __shfl(g, 16 * t + (lane >> 2));
            vfloat4 v = { gq * sc0, gq * sc1, gq * sc2, gq * sc3 };
            if (r == 0 && t == 0) {
                // diag: q' = lane>>2 (<16), abs where channel==q' ->
                // c == q'>>2, component q'&3
                const int qq = lane >> 2;
                if ((qq >> 2) == c) {
                    const int r2 = qq & 3;
                    v[r2] = fabsf(v[r2]);
                }
            }
            rowp[s * 64 + lane] = v;   // plain store (was nontemporal)
        }
    }
}

extern "C" void kernel_launch(void* const* d_in, const int* in_sizes, int n_in,
                              void* d_out, int out_size, void* d_ws, size_t ws_size,
                              hipStream_t stream) {
    const float* mu_in   = (const float*)d_in[0];
    const float* w_mu    = (const float*)d_in[1];
    const float* w_sigma = (const float*)d_in[2];
    float* out = (float*)d_out;

    dim3 grid(BATCH * P / 4);   // 2304 blocks, 1 p-row per wave
    dim3 block(NTHR);
    vdp_fused_kernel<<<grid, block, 0, stream>>>(mu_in, w_mu, w_sigma, out);
}

// Round 3
// 346.346 us; speedup vs baseline: 1.0048x; 1.0048x over previous
//
#include <hip/hip_runtime.h>
#include <math.h>

// B=16, H=W=28, C=1, KSIZE=5, KNUM=16, VALID stride-1 -> OH=OW=24, P=576.
#define BATCH 16
#define H     28
#define W     28
#define KS    5
#define KN    16
#define OHW   24
#define P     576           // = 9 * 64 exactly
#define NTHR  256           // 4 waves; one p-row per wave
#define MU_OUT_ELEMS (BATCH * P * KN)

typedef float vfloat4 __attribute__((ext_vector_type(4)));

__global__ __launch_bounds__(NTHR) void vdp_fused_kernel(
    const float* __restrict__ mu_in,    // [16,28,28,1]
    const float* __restrict__ w_mu,     // [5,5,1,16]
    const float* __restrict__ w_sigma,  // [16]
    float* __restrict__ out)
{
    __shared__ float mu_s[H * W];         // 3.1 KB
    __shared__ float wmu_s[KS * KS * KN]; // 1.6 KB
    __shared__ float sp_s[KN];

    const int tid  = threadIdx.x;
    const int wave = tid >> 6;
    const int lane = tid & 63;

    const int blocks_per_b = P / 4;     // 144 (4 p-rows per block, 1 per wave)
    const int b = blockIdx.x / blocks_per_b;
    const int p = (blockIdx.x % blocks_per_b) * 4 + wave;

    // Stage image, conv weights, softplus scales. ONE barrier total.
    const float* mu_b = mu_in + b * (H * W);
    for (int i = tid; i < H * W; i += NTHR) mu_s[i] = mu_b[i];
    for (int i = tid; i < KS * KS * KN; i += NTHR) wmu_s[i] = w_mu[i];
    if (tid < KN) sp_s[tid] = log1pf(expf(w_sigma[tid]));
    __syncthreads();

    const int ph = p / OHW;
    const int pw = p % OHW;

    // Patch p (wave-uniform LDS broadcast reads).
    float Xp[KS * KS];
    #pragma unroll
    for (int kh = 0; kh < KS; ++kh)
        #pragma unroll
        for (int kw = 0; kw < KS; ++kw)
            Xp[kh * KS + kw] = mu_s[(ph + kh) * W + (pw + kw)];

    // mu_out row: lanes 0..15, one output channel each.
    if (lane < KN) {
        float acc = 0.f;
        #pragma unroll
        for (int j = 0; j < KS * KS; ++j)
            acc += Xp[j] * wmu_s[j * KN + lane];
        out[(b * P + p) * KN + lane] = acc;
    }

    // This lane's 4 channels: c = lane&3 -> channels 4c..4c+3.
    const int c = lane & 3;
    const float sc0 = sp_s[4 * c + 0];
    const float sc1 = sp_s[4 * c + 1];
    const float sc2 = sp_s[4 * c + 2];
    const float sc3 = sp_s[4 * c + 3];

    vfloat4* rowp = (vfloat4*)(out + MU_OUT_ELEMS + (size_t)(b * P + p) * (P * KN));

    // ---- Phase A: compute the full Gram row, 9 values per lane, NO stores.
    // g[r] = <Xp, X_{64r+lane}>
    float g[9];
    #pragma unroll
    for (int r = 0; r < 9; ++r) {
        const int q  = r * 64 + lane;
        const int qh = q / OHW;
        const int qw = q % OHW;
        const float* mq = &mu_s[qh * W + qw];
        float acc = 0.f;
        #pragma unroll
        for (int kh = 0; kh < KS; ++kh)
            #pragma unroll
            for (int kw = 0; kw < KS; ++kw)
                acc += Xp[kh * KS + kw] * mq[kh * W + kw];
        g[r] = acc;
    }

    // ---- Phase B: all 36 cross-lane redistributions up front (independent
    // ds_permutes, no global stores interleaved -> no per-store lgkm gating).
    // Store s covers float4 f = 64s+lane: row pos q' = 16s+(lane>>2),
    // channels 4c..4c+3. gq[s] = g[s>>2] taken from lane 16*(s&3)+(lane>>2).
    float gq[36];
    #pragma unroll
    for (int s = 0; s < 36; ++s)
        gq[s] = __shfl(g[s >> 2], 16 * (s & 3) + (lane >> 2));

    // ---- Phase C: pure reg->global store burst, fill-kernel-like:
    // 36 independent 1 KB wave-stores with only 4 VALU muls between them.
    #pragma unroll
    for (int s = 0; s < 36; ++s) {
        vfloat4 v = { gq[s] * sc0, gq[s] * sc1, gq[s] * sc2, gq[s] * sc3 };
        if (s == 0) {
            // diag: q' = lane>>2 (<16), abs where channel==q' ->
            // c == q'>>2, component q'&3
            const int qq = lane >> 2;
            if ((qq >> 2) == c) {
                const int r2 = qq & 3;
                v[r2] = fabsf(v[r2]);
            }
        }
        rowp[s * 64 + lane] = v;
    }
}

extern "C" void kernel_launch(void* const* d_in, const int* in_sizes, int n_in,
                              void* d_out, int out_size, void* d_ws, size_t ws_size,
                              hipStream_t stream) {
    const float* mu_in   = (const float*)d_in[0];
    const float* w_mu    = (const float*)d_in[1];
    const float* w_sigma = (const float*)d_in[2];
    float* out = (float*)d_out;

    dim3 grid(BATCH * P / 4);   // 2304 blocks, 1 p-row per wave
    dim3 block(NTHR);
    vdp_fused_kernel<<<grid, block, 0, stream>>>(mu_in, w_mu, w_sigma, out);
}

// Round 4
// 345.226 us; speedup vs baseline: 1.0081x; 1.0032x over previous
//
#include <hip/hip_runtime.h>
#include <math.h>

// B=16, H=W=28, C=1, KSIZE=5, KNUM=16, VALID stride-1 -> OH=OW=24, P=576.
#define BATCH 16
#define H     28
#define W     28
#define KS    5
#define KN    16
#define OHW   24
#define P     576           // = 9 * 64 exactly
#define NTHR  256           // 4 waves; one p-row per wave
#define NGRP  (BATCH * P / 4)   // 2304 row-groups (4 p-rows each)
#define GRID  512               // persistent-ish: 2 blocks/CU, 8 waves/CU
#define MU_OUT_ELEMS (BATCH * P * KN)

typedef float vfloat4 __attribute__((ext_vector_type(4)));

__global__ __launch_bounds__(NTHR) void vdp_fused_kernel(
    const float* __restrict__ mu_in,    // [16,28,28,1]
    const float* __restrict__ w_mu,     // [5,5,1,16]
    const float* __restrict__ w_sigma,  // [16]
    float* __restrict__ out)
{
    __shared__ float mu_s[H * W];         // 3.1 KB
    __shared__ float wmu_s[KS * KS * KN]; // 1.6 KB
    __shared__ float sp_s[KN];

    const int tid  = threadIdx.x;
    const int wave = tid >> 6;
    const int lane = tid & 63;
    const int c = lane & 3;               // this lane's channel group

    // One-time staging of conv weights + softplus scales.
    for (int i = tid; i < KS * KS * KN; i += NTHR) wmu_s[i] = w_mu[i];
    if (tid < KN) sp_s[tid] = log1pf(expf(w_sigma[tid]));

    int prev_b = -1;

    // Grid-stride over row-groups IN OUTPUT-ADDRESS ORDER. At any instant,
    // the ~512 resident blocks write a contiguous ~75 MB window that
    // advances like the fill kernel's sweep (fits in 256 MB L3), instead of
    // 2304 blocks statically spread across the whole 340 MB output.
    for (int grp = (int)blockIdx.x; grp < NGRP; grp += (int)gridDim.x) {
        const int b = grp / (P / 4);
        const int p = (grp % (P / 4)) * 4 + wave;

        if (b != prev_b) {                // block-uniform branch
            __syncthreads();              // prior iter's mu_s reads done
            const float* mu_b = mu_in + b * (H * W);
            for (int i = tid; i < H * W; i += NTHR) mu_s[i] = mu_b[i];
            __syncthreads();              // mu_s (and first-iter sp_s/wmu_s) ready
            prev_b = b;
        }

        const int ph = p / OHW;
        const int pw = p % OHW;

        // Patch p (wave-uniform LDS broadcast reads).
        float Xp[KS * KS];
        #pragma unroll
        for (int kh = 0; kh < KS; ++kh)
            #pragma unroll
            for (int kw = 0; kw < KS; ++kw)
                Xp[kh * KS + kw] = mu_s[(ph + kh) * W + (pw + kw)];

        // mu_out row: lanes 0..15, one output channel each.
        if (lane < KN) {
            float acc = 0.f;
            #pragma unroll
            for (int j = 0; j < KS * KS; ++j)
                acc += Xp[j] * wmu_s[j * KN + lane];
            out[(b * P + p) * KN + lane] = acc;
        }

        const float sc0 = sp_s[4 * c + 0];
        const float sc1 = sp_s[4 * c + 1];
        const float sc2 = sp_s[4 * c + 2];
        const float sc3 = sp_s[4 * c + 3];

        vfloat4* rowp = (vfloat4*)(out + MU_OUT_ELEMS +
                                   (size_t)(b * P + p) * (P * KN));

        // Phase A: full Gram row, 9 values per lane, no stores.
        float g[9];
        #pragma unroll
        for (int r = 0; r < 9; ++r) {
            const int q  = r * 64 + lane;
            const int qh = q / OHW;
            const int qw = q % OHW;
            const float* mq = &mu_s[qh * W + qw];
            float acc = 0.f;
            #pragma unroll
            for (int kh = 0; kh < KS; ++kh)
                #pragma unroll
                for (int kw = 0; kw < KS; ++kw)
                    acc += Xp[kh * KS + kw] * mq[kh * W + kw];
            g[r] = acc;
        }

        // Phase B: all 36 cross-lane redistributions (independent permutes).
        // Store s covers float4 f = 64s+lane: row pos q' = 16s+(lane>>2);
        // gq[s] = g[s>>2] from lane 16*(s&3)+(lane>>2).
        float gq[36];
        #pragma unroll
        for (int s = 0; s < 36; ++s)
            gq[s] = __shfl(g[s >> 2], 16 * (s & 3) + (lane >> 2));

        // Phase C: pure reg->global store burst (36 x 1 KB wave-stores).
        #pragma unroll
        for (int s = 0; s < 36; ++s) {
            vfloat4 v = { gq[s] * sc0, gq[s] * sc1, gq[s] * sc2, gq[s] * sc3 };
            if (s == 0) {
                // diag: q' = lane>>2 (<16), abs where channel==q' ->
                // c == q'>>2, component q'&3 (p-independent)
                const int qq = lane >> 2;
                if ((qq >> 2) == c) {
                    const int r2 = qq & 3;
                    v[r2] = fabsf(v[r2]);
                }
            }
            rowp[s * 64 + lane] = v;
        }
    }
}

extern "C" void kernel_launch(void* const* d_in, const int* in_sizes, int n_in,
                              void* d_out, int out_size, void* d_ws, size_t ws_size,
                              hipStream_t stream) {
    const float* mu_in   = (const float*)d_in[0];
    const float* w_mu    = (const float*)d_in[1];
    const float* w_sigma = (const float*)d_in[2];
    float* out = (float*)d_out;

    dim3 grid(GRID);    // 512 persistent-ish blocks, grid-stride over 2304 groups
    dim3 block(NTHR);
    vdp_fused_kernel<<<grid, block, 0, stream>>>(mu_in, w_mu, w_sigma, out);
}